// Round 4
// baseline (208.767 us; speedup 1.0000x reference)
//
#include <hip/hip_runtime.h>

#define HW 32
#define NPIX 1024      // 32*32
#define IMG 3072       // 3*32*32
#define IPB 8          // images per block: grid 1024 = 4 blocks/CU, 1 generation

typedef float vf4 __attribute__((ext_vector_type(4)));

// ---------------- threefry2x32 (exact JAX semantics) ----------------
__device__ __forceinline__ unsigned rotl32(unsigned x, int d) {
    return (x << d) | (x >> (32 - d));
}

struct UPair { unsigned a, b; };

__device__ __forceinline__ UPair threefry2x32(unsigned k0, unsigned k1,
                                              unsigned x0, unsigned x1) {
    unsigned k2 = k0 ^ k1 ^ 0x1BD11BDAu;
    x0 += k0; x1 += k1;
#define RND(r) { x0 += x1; x1 = rotl32(x1, (r)); x1 ^= x0; }
    RND(13) RND(15) RND(26) RND(6)
    x0 += k1; x1 += k2 + 1u;
    RND(17) RND(29) RND(16) RND(24)
    x0 += k2; x1 += k0 + 2u;
    RND(13) RND(15) RND(26) RND(6)
    x0 += k0; x1 += k1 + 3u;
    RND(17) RND(29) RND(16) RND(24)
    x0 += k1; x1 += k2 + 4u;
    RND(13) RND(15) RND(26) RND(6)
    x0 += k2; x1 += k0 + 5u;
#undef RND
    return {x0, x1};
}

__device__ __forceinline__ float bits_to_u01(unsigned bits) {
    return __uint_as_float((bits >> 9) | 0x3f800000u) - 1.0f;
}

// reference _reflect with lo=-0.5, span=32 — fmod-free (exact for pow-2 span)
__device__ __forceinline__ float reflect32(float c) {
    float t = fabsf(c + 0.5f);
    float flips = floorf(t * 0.03125f);
    float extra = fmaf(flips, -32.0f, t);
    float o = (((int)flips) & 1) ? (31.5f - extra) : (extra - 0.5f);
    return fminf(fmaxf(o, 0.0f), 31.0f);
}

__device__ __forceinline__ float rfl_f(float v) {
    return __uint_as_float(__builtin_amdgcn_readfirstlane(__float_as_uint(v)));
}
__device__ __forceinline__ int rfl_i(int v) {
    return __builtin_amdgcn_readfirstlane(v);
}

// 256 threads / 4 waves. STRIDED ownership (thread t: column x=t&31, rows
// yr+8i) -> every linear LDS b128 access is conflict-free (R3-verified).
// Ping-pong buffers S/C alternate by image parity; per-image barrier count
// is 3 (stage|crop|blur) vs 5 in the monolithic version. Global loads and
// RNG for image k+1 are issued during image k's compute.
__global__ __launch_bounds__(256) void aug_kernel(
    const float* __restrict__ xin, const float* __restrict__ aff,
    const int* __restrict__ apply_crop, float* __restrict__ out, int B) {
    __shared__ vf4 bufA[NPIX];
    __shared__ vf4 bufB[NPIX];
    __shared__ float s_pf[2][9];   // [slot]{th0..5, br, ct, sa}
    __shared__ int   s_pi[2][7];   // [slot]{top,left,flip,hue,gray,blur,solar}

    const int t = threadIdx.x;
    const int x = t & 31;
    const int yr = t >> 5;
    const bool do_crop = (apply_crop[0] != 0);
    const size_t OUT_IMG = (size_t)B * IMG;
    const int img0 = blockIdx.x * IPB;

    // ---- image-independent per-thread geometry, hoisted out of the loop ----
    float dxv = fmaxf(fmaf((float)x, 0.78125f, -0.109375f), 0.0f);
    const int q0 = (int)dxv; const float lx = dxv - (float)q0;
    const int q1 = min(q0 + 1, 24);
    const float omx_c = 1.0f - lx;
    const float xn = (float)x * 0.0625f - 0.96875f;
    int i0a[4], i1a[4]; float lya[4], yna[4];
#pragma unroll
    for (int i = 0; i < 4; ++i) {
        int yi = yr + 8 * i;
        float dy = fmaxf(fmaf((float)yi, 0.78125f, -0.109375f), 0.0f);
        i0a[i] = (int)dy; lya[i] = dy - (float)i0a[i];
        i1a[i] = min(i0a[i] + 1, 24);
        yna[i] = (float)yi * 0.0625f - 0.96875f;
    }

    // ---- per-image RNG/theta -> param slot (jax_threefry_partitionable) ----
    auto compute_params = [&](int bb, int slot) {
        if (t < 6) s_pf[slot][t] = aff[(size_t)bb * 6 + t];
        if (t < 10) {
            int kk = t;
            UPair K = threefry2x32(0u, 42u, 0u, (unsigned)kk);  // ks[kk]
            if (kk < 2) {
                UPair k2 = threefry2x32(K.a, K.b, 0u, 1u);
                UPair r = threefry2x32(k2.a, k2.b, 0u, (unsigned)bb);
                s_pi[slot][kk] = (int)((r.a ^ r.b) & 7u);       // top / left
            } else {
                UPair r = threefry2x32(K.a, K.b, 0u, (unsigned)bb);
                float u = bits_to_u01(r.a ^ r.b);
                if      (kk == 2) s_pi[slot][2] = (u < 0.5f);
                else if (kk == 3) s_pf[slot][6] = 1.0f + (u - 0.5f) * 0.8f;
                else if (kk == 4) s_pf[slot][7] = 1.0f + (u - 0.5f) * 0.8f;
                else if (kk == 5) s_pf[slot][8] = 1.0f + (u - 0.5f) * 0.8f;
                else if (kk == 6) s_pi[slot][3] = (u < 0.5f);
                else if (kk == 7) s_pi[slot][4] = (u < 0.2f);
                else if (kk == 8) s_pi[slot][5] = (u < 0.5f);
                else              s_pi[slot][6] = (u < 0.1f);
            }
        }
    };

    // ---- prologue: image 0 loads + params ----
    float g0[4], g1[4], g2[4];
    {
        const float* src = xin + (size_t)img0 * IMG;
#pragma unroll
        for (int i = 0; i < 4; ++i) {
            int p = t + 256 * i;
            g0[i] = src[p]; g1[i] = src[NPIX + p]; g2[i] = src[2 * NPIX + p];
        }
    }
    compute_params(img0, 0);
    __syncthreads();   // slot 0 visible

    for (int k = 0; k < IPB; ++k) {
        const int b = img0 + k;
        if (b >= B) break;                    // block-uniform
        const int par = k & 1;
        vf4* S = par ? bufB : bufA;           // stage target
        vf4* C = par ? bufA : bufB;           // crop target

        // ---- stage (denorm) from prefetched regs ----
#pragma unroll
        for (int i = 0; i < 4; ++i) {
            vf4 v;
            v.x = fmaf(g0[i], 0.2675f, 0.5071f);
            v.y = fmaf(g1[i], 0.2565f, 0.4867f);
            v.z = fmaf(g2[i], 0.2761f, 0.4408f);
            v.w = 0.0f;
            S[t + 256 * i] = v;
        }

        // ---- prefetch image k+1 (+ its params into the other slot) ----
        // Issued here so HBM/threefry latency hides under this image's phases.
        if (k + 1 < IPB && b + 1 < B) {
            const float* src = xin + (size_t)(b + 1) * IMG;
#pragma unroll
            for (int i = 0; i < 4; ++i) {
                int p = t + 256 * i;
                g0[i] = src[p]; g1[i] = src[NPIX + p]; g2[i] = src[2 * NPIX + p];
            }
            compute_params(b + 1, par ^ 1);   // writes slot par^1 only (disjoint)
        }

        // ---- passthrough outputs for this image (slot par, already visible) ----
        if (t == 0) out[OUT_IMG + b] = s_pi[par][2] ? 1.0f : 0.0f;
        if (t < 6)  out[OUT_IMG + (size_t)B + (size_t)b * 6 + t] = s_pf[par][t];

        __syncthreads();   // (1) S staged; also publishes slot par^1 for next iter

        const int top  = rfl_i(s_pi[par][0]), left = rfl_i(s_pi[par][1]);
        const int flip = rfl_i(s_pi[par][2]), hue  = rfl_i(s_pi[par][3]);
        const int gray = rfl_i(s_pi[par][4]), blur = rfl_i(s_pi[par][5]);
        const int solar = rfl_i(s_pi[par][6]);
        const float br   = rfl_f(s_pf[par][6]);
        const float ctsa = rfl_f(s_pf[par][7]) * rfl_f(s_pf[par][8]);
        const float th0 = rfl_f(s_pf[par][0]), th1 = rfl_f(s_pf[par][1]);
        const float th2 = rfl_f(s_pf[par][2]), th3 = rfl_f(s_pf[par][3]);
        const float th4 = rfl_f(s_pf[par][4]), th5 = rfl_f(s_pf[par][5]);

        vf4* cur;
        vf4* freeb;
        float cx[4], cy[4], cz[4];

        // ---- crop-resize S -> C (different buffers: no read/write barrier) ----
        if (do_crop) {
            const int c0 = left + q0, c1 = left + q1;
#pragma unroll
            for (int i = 0; i < 4; ++i) {
                int r0 = (top + i0a[i]) << 5, r1 = (top + i1a[i]) << 5;
                float ly = lya[i], omy = 1.0f - ly;
                float w00 = omy * omx_c, w01 = omy * lx;
                float w10 = ly * omx_c, w11 = ly * lx;
                vf4 t00 = S[r0 + c0], t01 = S[r0 + c1];
                vf4 t10 = S[r1 + c0], t11 = S[r1 + c1];
                cx[i] = fmaf(t00.x, w00, fmaf(t01.x, w01, fmaf(t10.x, w10, t11.x * w11)));
                cy[i] = fmaf(t00.y, w00, fmaf(t01.y, w01, fmaf(t10.y, w10, t11.y * w11)));
                cz[i] = fmaf(t00.z, w00, fmaf(t01.z, w01, fmaf(t10.z, w10, t11.z * w11)));
            }
#pragma unroll
            for (int i = 0; i < 4; ++i) {
                vf4 v; v.x = cx[i]; v.y = cy[i]; v.z = cz[i]; v.w = 0.0f;
                C[t + 256 * i] = v;
            }
            __syncthreads();   // (2) C visible
            cur = C; freeb = S;
        } else {
            cur = S; freeb = C;
        }

        // ---- grid sample (flip folded) + fused color chain (regs) ----
#pragma unroll
        for (int i = 0; i < 4; ++i) {
            float gx = fmaf(th0, xn, fmaf(th1, yna[i], th2));
            float gy = fmaf(th3, xn, fmaf(th4, yna[i], th5));
            float ix = reflect32(fmaf(gx, 16.0f, 15.5f));
            float iy = reflect32(fmaf(gy, 16.0f, 15.5f));
            float fy = floorf(iy), fx = floorf(ix);
            float wy = iy - fy, wx = ix - fx;
            int y0 = (int)fy; int y1 = min(y0 + 1, 31);
            int x0 = (int)fx; int x1 = min(x0 + 1, 31);
            if (flip) { x0 = 31 - x0; x1 = 31 - x1; }
            int r0 = y0 << 5, r1 = y1 << 5;
            float omy = 1.0f - wy, omx = 1.0f - wx;
            float w00 = omy * omx, w01 = omy * wx;
            float w10 = wy * omx, w11 = wy * wx;
            vf4 t00 = cur[r0 + x0], t01 = cur[r0 + x1];
            vf4 t10 = cur[r1 + x0], t11 = cur[r1 + x1];
            float ch0 = fmaf(t00.x, w00, fmaf(t01.x, w01, fmaf(t10.x, w10, t11.x * w11)));
            float ch1 = fmaf(t00.y, w00, fmaf(t01.y, w01, fmaf(t10.y, w10, t11.y * w11)));
            float ch2 = fmaf(t00.z, w00, fmaf(t01.z, w01, fmaf(t10.z, w10, t11.z * w11)));
            ch0 *= br; ch1 *= br; ch2 *= br;
            float g = (ch0 + ch1 + ch2) * (1.0f / 3.0f);
            ch0 = fmaf(ch0 - g, ctsa, g);
            ch1 = fmaf(ch1 - g, ctsa, g);
            ch2 = fmaf(ch2 - g, ctsa, g);
            if (hue) { float tmp = ch0; ch0 = ch2; ch2 = tmp; }
            if (gray) { ch0 = ch1 = ch2 = g; }
            cx[i] = ch0; cy[i] = ch1; cz[i] = ch2;
        }

        // ---- blur: H-pass via lane shuffles, V-pass via the retired buffer ----
        if (blur) {
            const int tl = t - 1, tr = t + 1;
            float hx[4], hy[4], hz[4];
#pragma unroll
            for (int i = 0; i < 4; ++i) {
                float v, lf, rt;
                v = cx[i]; lf = __shfl(v, tl); rt = __shfl(v, tr);
                if (x == 0) lf = v;  if (x == 31) rt = v;
                hx[i] = lf + v + rt;
                v = cy[i]; lf = __shfl(v, tl); rt = __shfl(v, tr);
                if (x == 0) lf = v;  if (x == 31) rt = v;
                hy[i] = lf + v + rt;
                v = cz[i]; lf = __shfl(v, tl); rt = __shfl(v, tr);
                if (x == 0) lf = v;  if (x == 31) rt = v;
                hz[i] = lf + v + rt;
            }
            // freeb's prior reads retired at (2) (crop) / prev end-bar (!crop)
#pragma unroll
            for (int i = 0; i < 4; ++i) {
                vf4 v; v.x = hx[i]; v.y = hy[i]; v.z = hz[i]; v.w = 0.0f;
                freeb[t + 256 * i] = v;
            }
            __syncthreads();   // (3) H visible
#pragma unroll
            for (int i = 0; i < 4; ++i) {
                int yi = yr + 8 * i;
                vf4 up = freeb[(max(yi - 1, 0) << 5) + x];
                vf4 dn = freeb[(min(yi + 1, 31) << 5) + x];
                cx[i] = (up.x + hx[i] + dn.x) * (1.0f / 9.0f);
                cy[i] = (up.y + hy[i] + dn.y) * (1.0f / 9.0f);
                cz[i] = (up.z + hz[i] + dn.z) * (1.0f / 9.0f);
            }
        }

        // ---- solarize + clip + renorm + planar coalesced stores ----
        {
            const float INV0 = 1.0f / 0.2675f, INV1 = 1.0f / 0.2565f, INV2 = 1.0f / 0.2761f;
            float* o = out + (size_t)b * IMG;
#pragma unroll
            for (int i = 0; i < 4; ++i) {
                int p = t + 256 * i;
                float r0v = cx[i], r1v = cy[i], r2v = cz[i];
                if (solar) {
                    if (r0v > 0.5f) r0v = 1.0f - r0v;
                    if (r1v > 0.5f) r1v = 1.0f - r1v;
                    if (r2v > 0.5f) r2v = 1.0f - r2v;
                }
                r0v = fminf(fmaxf(r0v, 0.0f), 1.0f);
                r1v = fminf(fmaxf(r1v, 0.0f), 1.0f);
                r2v = fminf(fmaxf(r2v, 0.0f), 1.0f);
                o[p]            = (r0v - 0.5071f) * INV0;
                o[NPIX + p]     = (r1v - 0.4867f) * INV1;
                o[2 * NPIX + p] = (r2v - 0.4408f) * INV2;
            }
        }

        // WAR guard for next iteration's stage into C_k / crop into S_k:
        //  crop&&blur : sample-reads of C retired at (3); V-reads of S retired
        //               at next iter's (1) before its crop writes S — no bar.
        //  crop&&!blur: sample-reads of C unretired -> bar.
        //  !crop&&blur: V-reads of C (=freeb) unretired -> bar.
        //  !crop&&!blur: bar harmless (keeps logic simple).
        if (!(do_crop && blur)) __syncthreads();
    }
}

extern "C" void kernel_launch(void* const* d_in, const int* in_sizes, int n_in,
                              void* d_out, int out_size, void* d_ws, size_t ws_size,
                              hipStream_t stream) {
    const float* x = (const float*)d_in[0];
    const float* aff = (const float*)d_in[1];
    const int* ac = (const int*)d_in[2];
    float* out = (float*)d_out;
    int B = in_sizes[0] / IMG;
    int grid = (B + IPB - 1) / IPB;
    aug_kernel<<<dim3(grid), dim3(256), 0, stream>>>(x, aff, ac, out, B);
}

// Round 5
// 191.699 us; speedup vs baseline: 1.0890x; 1.0890x over previous
//
#include <hip/hip_runtime.h>

#define HW 32
#define NPIX 1024      // 32*32
#define IMG 3072       // 3*32*32

typedef float vf4 __attribute__((ext_vector_type(4)));

// ---------------- threefry2x32 (exact JAX semantics) ----------------
__device__ __forceinline__ unsigned rotl32(unsigned x, int d) {
    return (x << d) | (x >> (32 - d));
}

struct UPair { unsigned a, b; };

__device__ __forceinline__ UPair threefry2x32(unsigned k0, unsigned k1,
                                              unsigned x0, unsigned x1) {
    unsigned k2 = k0 ^ k1 ^ 0x1BD11BDAu;
    x0 += k0; x1 += k1;
#define RND(r) { x0 += x1; x1 = rotl32(x1, (r)); x1 ^= x0; }
    RND(13) RND(15) RND(26) RND(6)
    x0 += k1; x1 += k2 + 1u;
    RND(17) RND(29) RND(16) RND(24)
    x0 += k2; x1 += k0 + 2u;
    RND(13) RND(15) RND(26) RND(6)
    x0 += k0; x1 += k1 + 3u;
    RND(17) RND(29) RND(16) RND(24)
    x0 += k1; x1 += k2 + 4u;
    RND(13) RND(15) RND(26) RND(6)
    x0 += k2; x1 += k0 + 5u;
#undef RND
    return {x0, x1};
}

__device__ __forceinline__ float bits_to_u01(unsigned bits) {
    return __uint_as_float((bits >> 9) | 0x3f800000u) - 1.0f;
}

// reference _reflect with lo=-0.5, span=32 — fmod-free (exact for pow-2 span)
__device__ __forceinline__ float reflect32(float c) {
    float t = fabsf(c + 0.5f);
    float flips = floorf(t * 0.03125f);
    float extra = fmaf(flips, -32.0f, t);
    float o = (((int)flips) & 1) ? (31.5f - extra) : (extra - 0.5f);
    return fminf(fmaxf(o, 0.0f), 31.0f);
}

// ONE WAVE PER IMAGE, ZERO BARRIERS (wave-private correctness proven in an
// earlier passing version: a wave's DS ops execute in program order, and the
// compiler preserves read->write order on may-alias LDS, so "read-all-taps
// then write-back" phases are race-free without __syncthreads).
// STRIDED ownership fixes that version's fatal bank conflicts: lane l owns
// column x=l&31, rows y=(l>>5)+2i  =>  every wave-wide vf4 access covers 64
// consecutive pixels = 1024 consecutive bytes = each bank hit exactly 8x
// (the hard minimum). LDS = exactly 16 KB -> ~10 independent waves/CU that
// drift through phases freely (no convoy).
__global__ __launch_bounds__(64) void aug_kernel(
    const float* __restrict__ xin, const float* __restrict__ aff,
    const int* __restrict__ apply_crop, float* __restrict__ out, int B) {
    __shared__ vf4 buf[NPIX];

    const int b = blockIdx.x;
    const int l = threadIdx.x;        // 0..63
    const int x = l & 31;             // fixed column
    const int yb = l >> 5;            // rows y = yb + 2*i, i = 0..15
    const bool do_crop = (apply_crop[0] != 0);
    const size_t OUT_IMG = (size_t)B * IMG;

    // ---- theta: block-uniform -> scalar loads ----
    const float th0 = aff[b * 6 + 0], th1 = aff[b * 6 + 1], th2 = aff[b * 6 + 2];
    const float th3 = aff[b * 6 + 3], th4 = aff[b * 6 + 4], th5 = aff[b * 6 + 5];

    // ---- issue global image loads early (strided, lane-consecutive) ----
    const float* src = xin + (size_t)b * IMG;
    float g0[16], g1[16], g2[16];
#pragma unroll
    for (int i = 0; i < 16; ++i) {
        int p = l + 64 * i;
        g0[i] = src[p];
        g1[i] = src[NPIX + p];
        g2[i] = src[2 * NPIX + p];
    }

    // ---- per-image RNG in lanes 0..9, broadcast via shuffle (no LDS) ----
    // jax_threefry_partitionable: ks[k] = threefry(0,42, 0,k);
    // bits(key,b) = r.a^r.b with r = threefry(key, 0, b);
    // randint: child key k2 = threefry(key,0,1), val = bits(k2,b) & 7.
    float fval = 0.0f; int ival = 0;
    if (l < 10) {
        UPair K = threefry2x32(0u, 42u, 0u, (unsigned)l);
        if (l < 2) {
            UPair k2 = threefry2x32(K.a, K.b, 0u, 1u);
            UPair r = threefry2x32(k2.a, k2.b, 0u, (unsigned)b);
            ival = (int)((r.a ^ r.b) & 7u);
        } else {
            UPair r = threefry2x32(K.a, K.b, 0u, (unsigned)b);
            float u = bits_to_u01(r.a ^ r.b);
            if      (l == 2) ival = (u < 0.5f);
            else if (l == 3) fval = 1.0f + (u - 0.5f) * 0.8f;
            else if (l == 4) fval = 1.0f + (u - 0.5f) * 0.8f;
            else if (l == 5) fval = 1.0f + (u - 0.5f) * 0.8f;
            else if (l == 6) ival = (u < 0.5f);
            else if (l == 7) ival = (u < 0.2f);
            else if (l == 8) ival = (u < 0.5f);
            else             ival = (u < 0.1f);
        }
    }
    const int top  = __shfl(ival, 0), left = __shfl(ival, 1);
    const int flip = __shfl(ival, 2), hue  = __shfl(ival, 6);
    const int gray = __shfl(ival, 7), blur = __shfl(ival, 8);
    const int solar = __shfl(ival, 9);
    const float br   = __shfl(fval, 3);
    const float ctsa = __shfl(fval, 4) * __shfl(fval, 5);  // contrast preserves mean

    if (l == 0) out[OUT_IMG + b] = flip ? 1.0f : 0.0f;
    if (l < 6)  out[OUT_IMG + (size_t)B + (size_t)b * 6 + l] = aff[b * 6 + l];

    // ---- denormalize + stage pixel-major vf4 (conflict-free b128) ----
#pragma unroll
    for (int i = 0; i < 16; ++i) {
        vf4 v;
        v.x = fmaf(g0[i], 0.2675f, 0.5071f);
        v.y = fmaf(g1[i], 0.2565f, 0.4867f);
        v.z = fmaf(g2[i], 0.2761f, 0.4408f);
        v.w = 0.0f;
        buf[l + 64 * i] = v;
    }

    float cx[16], cy[16], cz[16];

    // ---- crop-resize, in place: ALL reads (loop 1) precede writes (loop 2) ----
    if (do_crop) {
        float dxv = fmaxf(fmaf((float)x, 0.78125f, -0.109375f), 0.0f);
        int q0 = (int)dxv; float lx = dxv - (float)q0; int q1 = min(q0 + 1, 24);
        int c0 = left + q0, c1 = left + q1;
        float omx = 1.0f - lx;
#pragma unroll
        for (int i = 0; i < 16; ++i) {
            int y = yb + 2 * i;
            float dy = fmaxf(fmaf((float)y, 0.78125f, -0.109375f), 0.0f);
            int i0 = (int)dy; float ly = dy - (float)i0; int i1 = min(i0 + 1, 24);
            int r0 = (top + i0) << 5, r1 = (top + i1) << 5;
            float omy = 1.0f - ly;
            float w00 = omy * omx, w01 = omy * lx;
            float w10 = ly * omx, w11 = ly * lx;
            vf4 t00 = buf[r0 + c0], t01 = buf[r0 + c1];
            vf4 t10 = buf[r1 + c0], t11 = buf[r1 + c1];
            cx[i] = fmaf(t00.x, w00, fmaf(t01.x, w01, fmaf(t10.x, w10, t11.x * w11)));
            cy[i] = fmaf(t00.y, w00, fmaf(t01.y, w01, fmaf(t10.y, w10, t11.y * w11)));
            cz[i] = fmaf(t00.z, w00, fmaf(t01.z, w01, fmaf(t10.z, w10, t11.z * w11)));
        }
#pragma unroll
        for (int i = 0; i < 16; ++i) {
            vf4 v; v.x = cx[i]; v.y = cy[i]; v.z = cz[i]; v.w = 0.0f;
            buf[l + 64 * i] = v;
        }
    }

    // ---- grid sample (flip folded) + fused color chain (regs only) ----
    {
        const float xn = (float)x * 0.0625f - 0.96875f;
#pragma unroll
        for (int i = 0; i < 16; ++i) {
            int y = yb + 2 * i;
            float yn = (float)y * 0.0625f - 0.96875f;
            float gx = fmaf(th0, xn, fmaf(th1, yn, th2));
            float gy = fmaf(th3, xn, fmaf(th4, yn, th5));
            float ix = reflect32(fmaf(gx, 16.0f, 15.5f));
            float iy = reflect32(fmaf(gy, 16.0f, 15.5f));
            float fy = floorf(iy), fx = floorf(ix);
            float wy = iy - fy, wx = ix - fx;
            int y0 = (int)fy; int y1 = min(y0 + 1, 31);
            int x0 = (int)fx; int x1 = min(x0 + 1, 31);
            if (flip) { x0 = 31 - x0; x1 = 31 - x1; }
            int r0 = y0 << 5, r1 = y1 << 5;
            float omy = 1.0f - wy, omx = 1.0f - wx;
            float w00 = omy * omx, w01 = omy * wx;
            float w10 = wy * omx, w11 = wy * wx;
            vf4 t00 = buf[r0 + x0], t01 = buf[r0 + x1];
            vf4 t10 = buf[r1 + x0], t11 = buf[r1 + x1];
            float ch0 = fmaf(t00.x, w00, fmaf(t01.x, w01, fmaf(t10.x, w10, t11.x * w11)));
            float ch1 = fmaf(t00.y, w00, fmaf(t01.y, w01, fmaf(t10.y, w10, t11.y * w11)));
            float ch2 = fmaf(t00.z, w00, fmaf(t01.z, w01, fmaf(t10.z, w10, t11.z * w11)));
            ch0 *= br; ch1 *= br; ch2 *= br;
            float g = (ch0 + ch1 + ch2) * (1.0f / 3.0f);
            ch0 = fmaf(ch0 - g, ctsa, g);
            ch1 = fmaf(ch1 - g, ctsa, g);
            ch2 = fmaf(ch2 - g, ctsa, g);
            if (hue) { float tmp = ch0; ch0 = ch2; ch2 = tmp; }
            if (gray) { ch0 = ch1 = ch2 = g; }
            cx[i] = ch0; cy[i] = ch1; cz[i] = ch2;
        }
    }

    // ---- blur (wave-uniform): materialize -> H (x+-1 via LDS) -> V (y+-1) ----
    if (blur) {
        // materialize color (sample reads all retired: earlier in program order)
#pragma unroll
        for (int i = 0; i < 16; ++i) {
            vf4 v; v.x = cx[i]; v.y = cy[i]; v.z = cz[i]; v.w = 0.0f;
            buf[l + 64 * i] = v;
        }
        const int xm = max(x - 1, 0), xp = min(x + 1, 31);
        // H-pass: all 32 neighbor reads, center from regs (loop 1), then writes
#pragma unroll
        for (int i = 0; i < 16; ++i) {
            int yc = (yb + 2 * i) << 5;
            vf4 lf = buf[yc + xm];
            vf4 rt = buf[yc + xp];
            cx[i] = lf.x + cx[i] + rt.x;
            cy[i] = lf.y + cy[i] + rt.y;
            cz[i] = lf.z + cz[i] + rt.z;
        }
#pragma unroll
        for (int i = 0; i < 16; ++i) {
            vf4 v; v.x = cx[i]; v.y = cy[i]; v.z = cz[i]; v.w = 0.0f;
            buf[l + 64 * i] = v;
        }
        // V-pass: y+-1 rows written by other lanes — same-wave DS ordering
        // guarantees visibility; center H is in regs.
#pragma unroll
        for (int i = 0; i < 16; ++i) {
            int y = yb + 2 * i;
            vf4 up = buf[(max(y - 1, 0) << 5) + x];
            vf4 dn = buf[(min(y + 1, 31) << 5) + x];
            cx[i] = (up.x + cx[i] + dn.x) * (1.0f / 9.0f);
            cy[i] = (up.y + cy[i] + dn.y) * (1.0f / 9.0f);
            cz[i] = (up.z + cz[i] + dn.z) * (1.0f / 9.0f);
        }
    }

    // ---- solarize + clip + renorm + planar coalesced stores ----
    {
        const float INV0 = 1.0f / 0.2675f, INV1 = 1.0f / 0.2565f, INV2 = 1.0f / 0.2761f;
        float* o = out + (size_t)b * IMG;
#pragma unroll
        for (int i = 0; i < 16; ++i) {
            int p = l + 64 * i;
            float r0v = cx[i], r1v = cy[i], r2v = cz[i];
            if (solar) {
                if (r0v > 0.5f) r0v = 1.0f - r0v;
                if (r1v > 0.5f) r1v = 1.0f - r1v;
                if (r2v > 0.5f) r2v = 1.0f - r2v;
            }
            r0v = fminf(fmaxf(r0v, 0.0f), 1.0f);
            r1v = fminf(fmaxf(r1v, 0.0f), 1.0f);
            r2v = fminf(fmaxf(r2v, 0.0f), 1.0f);
            o[p]            = (r0v - 0.5071f) * INV0;
            o[NPIX + p]     = (r1v - 0.4867f) * INV1;
            o[2 * NPIX + p] = (r2v - 0.4408f) * INV2;
        }
    }
}

extern "C" void kernel_launch(void* const* d_in, const int* in_sizes, int n_in,
                              void* d_out, int out_size, void* d_ws, size_t ws_size,
                              hipStream_t stream) {
    const float* x = (const float*)d_in[0];
    const float* aff = (const float*)d_in[1];
    const int* ac = (const int*)d_in[2];
    float* out = (float*)d_out;
    int B = in_sizes[0] / IMG;
    aug_kernel<<<dim3(B), dim3(64), 0, stream>>>(x, aff, ac, out, B);
}

// Round 6
// 180.619 us; speedup vs baseline: 1.1558x; 1.0613x over previous
//
#include <hip/hip_runtime.h>

#define HW 32
#define NPIX 1024      // 32*32
#define IMG 3072       // 3*32*32

typedef float vf4 __attribute__((ext_vector_type(4)));

// ---------------- threefry2x32 (exact JAX semantics) ----------------
__device__ __forceinline__ unsigned rotl32(unsigned x, int d) {
    return (x << d) | (x >> (32 - d));
}

struct UPair { unsigned a, b; };

__device__ __forceinline__ UPair threefry2x32(unsigned k0, unsigned k1,
                                              unsigned x0, unsigned x1) {
    unsigned k2 = k0 ^ k1 ^ 0x1BD11BDAu;
    x0 += k0; x1 += k1;
#define RND(r) { x0 += x1; x1 = rotl32(x1, (r)); x1 ^= x0; }
    RND(13) RND(15) RND(26) RND(6)
    x0 += k1; x1 += k2 + 1u;
    RND(17) RND(29) RND(16) RND(24)
    x0 += k2; x1 += k0 + 2u;
    RND(13) RND(15) RND(26) RND(6)
    x0 += k0; x1 += k1 + 3u;
    RND(17) RND(29) RND(16) RND(24)
    x0 += k1; x1 += k2 + 4u;
    RND(13) RND(15) RND(26) RND(6)
    x0 += k2; x1 += k0 + 5u;
#undef RND
    return {x0, x1};
}

__device__ __forceinline__ float bits_to_u01(unsigned bits) {
    return __uint_as_float((bits >> 9) | 0x3f800000u) - 1.0f;
}

// reference _reflect with lo=-0.5, span=32 — fmod-free (exact for pow-2 span)
__device__ __forceinline__ float reflect32(float c) {
    float t = fabsf(c + 0.5f);
    float flips = floorf(t * 0.03125f);
    float extra = fmaf(flips, -32.0f, t);
    float o = (((int)flips) & 1) ? (31.5f - extra) : (extra - 0.5f);
    return fminf(fmaxf(o, 0.0f), 31.0f);
}

__device__ __forceinline__ float rfl_f(float v) {
    return __uint_as_float(__builtin_amdgcn_readfirstlane(__float_as_uint(v)));
}
__device__ __forceinline__ int rfl_i(int v) {
    return __builtin_amdgcn_readfirstlane(v);
}

// 256 threads / 4 waves per image (best measured structure: 65.0 µs).
// STRIDED ownership: thread t owns column x=t&31, rows y=(t>>5)+8i -> every
// linear LDS vf4 access covers 64 consecutive pixels = conflict-free b128.
// THIS ROUND'S ONLY CHANGE vs that version: bulk image stores are
// NON-TEMPORAL. Output is written once and never re-read; streaming it past
// L3 keeps the 100 MB input fully L3-resident (FETCH_SIZE was ~50 MB =
// input evicted by output write-allocate), cutting HBM traffic ~30%.
__global__ __launch_bounds__(256) void aug_kernel(
    const float* __restrict__ xin, const float* __restrict__ aff,
    const int* __restrict__ apply_crop, float* __restrict__ out, int B) {
    __shared__ vf4 buf[NPIX];
    __shared__ float s_theta[6];
    __shared__ int s_top, s_left, s_flip, s_hue, s_gray, s_blur, s_solar;
    __shared__ float s_bright, s_contr, s_sat;

    const int b = blockIdx.x;
    const int t = threadIdx.x;         // 0..255
    const int x = t & 31;              // fixed column per thread
    const int yr = t >> 5;             // row base; y_i = yr + 8*i
    const bool do_crop = (apply_crop[0] != 0);

    // ---- issue global planar loads early (lane-stride-1, coalesced) ----
    const float* src = xin + (size_t)b * IMG;
    float g0[4], g1[4], g2[4];
#pragma unroll
    for (int i = 0; i < 4; ++i) {
        int p = t + 256 * i;
        g0[i] = src[p];
        g1[i] = src[NPIX + p];
        g2[i] = src[2 * NPIX + p];
    }

    const size_t OUT_IMG = (size_t)B * IMG;
    if (t < 6) {  // theta into LDS + affine passthrough output
        float v = aff[b * 6 + t];
        s_theta[t] = v;
        out[OUT_IMG + (size_t)B + (size_t)b * 6 + t] = v;
    }

    // ---- per-image RNG (jax_threefry_partitionable=True semantics) ----
    if (t < 10) {
        int k = t;
        UPair K = threefry2x32(0u, 42u, 0u, (unsigned)k);  // ks[k]
        if (k < 2) {
            UPair k2 = threefry2x32(K.a, K.b, 0u, 1u);
            UPair r = threefry2x32(k2.a, k2.b, 0u, (unsigned)b);
            int val = (int)((r.a ^ r.b) & 7u);
            if (k == 0) s_top = val; else s_left = val;
        } else {
            UPair r = threefry2x32(K.a, K.b, 0u, (unsigned)b);
            float u = bits_to_u01(r.a ^ r.b);
            if      (k == 2) s_flip  = (u < 0.5f);
            else if (k == 3) s_bright = 1.0f + (u - 0.5f) * 0.8f;
            else if (k == 4) s_contr  = 1.0f + (u - 0.5f) * 0.8f;
            else if (k == 5) s_sat    = 1.0f + (u - 0.5f) * 0.8f;
            else if (k == 6) s_hue   = (u < 0.5f);
            else if (k == 7) s_gray  = (u < 0.2f);
            else if (k == 8) s_blur  = (u < 0.5f);
            else             s_solar = (u < 0.1f);
        }
    }

    // ---- denormalize + stage pixel-major (conflict-free b128 writes) ----
#pragma unroll
    for (int i = 0; i < 4; ++i) {
        vf4 v;
        v.x = fmaf(g0[i], 0.2675f, 0.5071f);
        v.y = fmaf(g1[i], 0.2565f, 0.4867f);
        v.z = fmaf(g2[i], 0.2761f, 0.4408f);
        v.w = 0.0f;
        buf[t + 256 * i] = v;
    }
    __syncthreads();

    if (t == 0) out[OUT_IMG + b] = s_flip ? 1.0f : 0.0f;
    const int top  = rfl_i(s_top),  left = rfl_i(s_left);
    const int flip = rfl_i(s_flip), hue  = rfl_i(s_hue);
    const int gray = rfl_i(s_gray), blur = rfl_i(s_blur), solar = rfl_i(s_solar);
    const float br   = rfl_f(s_bright);
    const float ctsa = rfl_f(s_contr) * rfl_f(s_sat);  // contrast preserves mean
    const float th0 = rfl_f(s_theta[0]), th1 = rfl_f(s_theta[1]), th2 = rfl_f(s_theta[2]);
    const float th3 = rfl_f(s_theta[3]), th4 = rfl_f(s_theta[4]), th5 = rfl_f(s_theta[5]);

    float cx[4], cy[4], cz[4];

    // ---- crop-resize: read phase (regs) | BAR | write-back ----
    if (do_crop) {
        // x-only math hoisted: one column index/fraction per thread
        float dxv = fmaxf(fmaf((float)x, 0.78125f, -0.109375f), 0.0f);
        int q0 = (int)dxv; float lx = dxv - (float)q0; int q1 = min(q0 + 1, 24);
        int c0 = left + q0, c1 = left + q1;
        float omx = 1.0f - lx;
#pragma unroll
        for (int i = 0; i < 4; ++i) {
            int yi = yr + 8 * i;
            float dy = fmaxf(fmaf((float)yi, 0.78125f, -0.109375f), 0.0f);
            int i0 = (int)dy; float ly = dy - (float)i0; int i1 = min(i0 + 1, 24);
            int r0 = (top + i0) << 5, r1 = (top + i1) << 5;
            float omy = 1.0f - ly;
            float w00 = omy * omx, w01 = omy * lx;
            float w10 = ly * omx, w11 = ly * lx;
            vf4 t00 = buf[r0 + c0], t01 = buf[r0 + c1];
            vf4 t10 = buf[r1 + c0], t11 = buf[r1 + c1];
            cx[i] = fmaf(t00.x, w00, fmaf(t01.x, w01, fmaf(t10.x, w10, t11.x * w11)));
            cy[i] = fmaf(t00.y, w00, fmaf(t01.y, w01, fmaf(t10.y, w10, t11.y * w11)));
            cz[i] = fmaf(t00.z, w00, fmaf(t01.z, w01, fmaf(t10.z, w10, t11.z * w11)));
        }
        __syncthreads();   // all reads done before in-place overwrite
#pragma unroll
        for (int i = 0; i < 4; ++i) {
            vf4 v; v.x = cx[i]; v.y = cy[i]; v.z = cz[i]; v.w = 0.0f;
            buf[t + 256 * i] = v;
        }
        __syncthreads();
    }

    // ---- grid sample (flip folded) + fused color chain (regs) ----
    {
        float xn = (float)x * 0.0625f - 0.96875f;   // hoisted
#pragma unroll
        for (int i = 0; i < 4; ++i) {
            int yi = yr + 8 * i;
            float yn = (float)yi * 0.0625f - 0.96875f;
            float gx = fmaf(th0, xn, fmaf(th1, yn, th2));
            float gy = fmaf(th3, xn, fmaf(th4, yn, th5));
            float ix = reflect32(fmaf(gx, 16.0f, 15.5f));
            float iy = reflect32(fmaf(gy, 16.0f, 15.5f));
            float fy = floorf(iy), fx = floorf(ix);
            float wy = iy - fy, wx = ix - fx;
            int y0 = (int)fy; int y1 = min(y0 + 1, 31);
            int x0 = (int)fx; int x1 = min(x0 + 1, 31);
            if (flip) { x0 = 31 - x0; x1 = 31 - x1; }
            int r0 = y0 << 5, r1 = y1 << 5;
            float omy = 1.0f - wy, omx = 1.0f - wx;
            float w00 = omy * omx, w01 = omy * wx;
            float w10 = wy * omx, w11 = wy * wx;
            vf4 t00 = buf[r0 + x0], t01 = buf[r0 + x1];
            vf4 t10 = buf[r1 + x0], t11 = buf[r1 + x1];
            float ch0 = fmaf(t00.x, w00, fmaf(t01.x, w01, fmaf(t10.x, w10, t11.x * w11)));
            float ch1 = fmaf(t00.y, w00, fmaf(t01.y, w01, fmaf(t10.y, w10, t11.y * w11)));
            float ch2 = fmaf(t00.z, w00, fmaf(t01.z, w01, fmaf(t10.z, w10, t11.z * w11)));
            ch0 *= br; ch1 *= br; ch2 *= br;
            float g = (ch0 + ch1 + ch2) * (1.0f / 3.0f);
            ch0 = fmaf(ch0 - g, ctsa, g);
            ch1 = fmaf(ch1 - g, ctsa, g);
            ch2 = fmaf(ch2 - g, ctsa, g);
            if (hue) { float tmp = ch0; ch0 = ch2; ch2 = tmp; }
            if (gray) { ch0 = ch1 = ch2 = g; }
            cx[i] = ch0; cy[i] = ch1; cz[i] = ch2;
        }
    }

    // ---- blur: H-pass via lane shuffles (x±1 = lane±1), V-pass via LDS ----
    if (blur) {
        __syncthreads();   // all sample reads done before overwrite
        const int tl = t - 1, tr = t + 1;
        float hx[4], hy[4], hz[4];
#pragma unroll
        for (int i = 0; i < 4; ++i) {
            float v, lf, rt;
            v = cx[i]; lf = __shfl(v, tl); rt = __shfl(v, tr);
            if (x == 0) lf = v;  if (x == 31) rt = v;
            hx[i] = lf + v + rt;
            v = cy[i]; lf = __shfl(v, tl); rt = __shfl(v, tr);
            if (x == 0) lf = v;  if (x == 31) rt = v;
            hy[i] = lf + v + rt;
            v = cz[i]; lf = __shfl(v, tl); rt = __shfl(v, tr);
            if (x == 0) lf = v;  if (x == 31) rt = v;
            hz[i] = lf + v + rt;
        }
#pragma unroll
        for (int i = 0; i < 4; ++i) {
            vf4 v; v.x = hx[i]; v.y = hy[i]; v.z = hz[i]; v.w = 0.0f;
            buf[t + 256 * i] = v;
        }
        __syncthreads();
#pragma unroll
        for (int i = 0; i < 4; ++i) {
            int yi = yr + 8 * i;
            vf4 up = buf[(max(yi - 1, 0) << 5) + x];
            vf4 dn = buf[(min(yi + 1, 31) << 5) + x];
            cx[i] = (up.x + hx[i] + dn.x) * (1.0f / 9.0f);
            cy[i] = (up.y + hy[i] + dn.y) * (1.0f / 9.0f);
            cz[i] = (up.z + hz[i] + dn.z) * (1.0f / 9.0f);
        }
    }

    // ---- solarize + clip + renorm + NON-TEMPORAL planar stores ----
    // Output is never re-read: stream it past L3 so the input stays resident.
    {
        const float INV0 = 1.0f / 0.2675f, INV1 = 1.0f / 0.2565f, INV2 = 1.0f / 0.2761f;
        float* o = out + (size_t)b * IMG;
#pragma unroll
        for (int i = 0; i < 4; ++i) {
            int p = t + 256 * i;
            float r0v = cx[i], r1v = cy[i], r2v = cz[i];
            if (solar) {
                if (r0v > 0.5f) r0v = 1.0f - r0v;
                if (r1v > 0.5f) r1v = 1.0f - r1v;
                if (r2v > 0.5f) r2v = 1.0f - r2v;
            }
            r0v = fminf(fmaxf(r0v, 0.0f), 1.0f);
            r1v = fminf(fmaxf(r1v, 0.0f), 1.0f);
            r2v = fminf(fmaxf(r2v, 0.0f), 1.0f);
            __builtin_nontemporal_store((r0v - 0.5071f) * INV0, o + p);
            __builtin_nontemporal_store((r1v - 0.4867f) * INV1, o + NPIX + p);
            __builtin_nontemporal_store((r2v - 0.4408f) * INV2, o + 2 * NPIX + p);
        }
    }
}

extern "C" void kernel_launch(void* const* d_in, const int* in_sizes, int n_in,
                              void* d_out, int out_size, void* d_ws, size_t ws_size,
                              hipStream_t stream) {
    const float* x = (const float*)d_in[0];
    const float* aff = (const float*)d_in[1];
    const int* ac = (const int*)d_in[2];
    float* out = (float*)d_out;
    int B = in_sizes[0] / IMG;
    aug_kernel<<<dim3(B), dim3(256), 0, stream>>>(x, aff, ac, out, B);
}